// Round 7
// baseline (11136.761 us; speedup 1.0000x reference)
//
#include <hip/hip_runtime.h>

// TRUTH KERNEL — EqProp MLP relaxation (784->128->128->10, B=16384, T=60).
// Deliberately zero-cleverness fp32 implementation to establish ground truth
// against the harness: exact reference semantics (synchronous/Jacobi update,
// tanh on all layers incl. last), fp32 math, library tanhf, separate kernel
// launches for the T-loop (global sync between steps), ping-pong state in d_ws.
//   h1' = tanh(c1 + h2@W1)          c1 = x@W0^T + b0   (loop-invariant)
//   h2' = tanh(b1 + h1@W1^T + h3@W2)
//   h3' = tanh(b2 + h2@W2^T)
// Output: (h1, h2, h3) concatenated flat, fp32.

#define NB 16384
#define D0 784
#define D1 128
#define D3 10
#define TSTEPS 60

// ws layout (floats): c1[NB*D1] | A: h1[NB*D1] h2[NB*D1] h3[NB*D3] | B: same
#define C1_OFF   0
#define HBUF_SZ  ((size_t)NB * (D1 + D1 + D3))
#define A_OFF    ((size_t)NB * D1)
#define B_OFF    (A_OFF + HBUF_SZ)
#define H2_REL   ((size_t)NB * D1)
#define H3_REL   ((size_t)2 * NB * D1)

// ---- init: state A <- (n1, n2, n3)
__global__ __launch_bounds__(128)
void k_init(const float* __restrict__ n1, const float* __restrict__ n2,
            const float* __restrict__ n3, float* __restrict__ A)
{
    const size_t b = blockIdx.x;
    const int j = threadIdx.x;
    A[b * D1 + j]          = n1[b * D1 + j];
    A[H2_REL + b * D1 + j] = n2[b * D1 + j];
    if (j < D3) A[H3_REL + b * D3 + j] = n3[b * D3 + j];
}

// ---- c1 = x @ W0^T + b0   (one block per batch row; x row staged in LDS)
__global__ __launch_bounds__(128)
void k_c1(const float* __restrict__ x, const float* __restrict__ W0,
          const float* __restrict__ b0, float* __restrict__ c1)
{
    __shared__ float xL[D0];
    const size_t b = blockIdx.x;
    const int j = threadIdx.x;
    for (int i = j; i < D0; i += 128) xL[i] = x[b * D0 + i];
    __syncthreads();
    float g = b0[j];
    const float* w = W0 + (size_t)j * D0;
    #pragma unroll 8
    for (int k = 0; k < D0; ++k) g += xL[k] * w[k];
    c1[b * D1 + j] = g;
}

// ---- one synchronous relaxation step: dst <- F(src)
__global__ __launch_bounds__(128)
void k_step(const float* __restrict__ src, float* __restrict__ dst,
            const float* __restrict__ c1,
            const float* __restrict__ W1, const float* __restrict__ b1,
            const float* __restrict__ W2, const float* __restrict__ b2)
{
    __shared__ float h1L[D1], h2L[D1], h3L[D3];
    const size_t b = blockIdx.x;
    const int j = threadIdx.x;
    h1L[j] = src[b * D1 + j];
    h2L[j] = src[H2_REL + b * D1 + j];
    if (j < D3) h3L[j] = src[H3_REL + b * D3 + j];
    __syncthreads();

    // g1 = c1 + h2 @ W1          -> (h2@W1)[j] = sum_k h2[k] * W1[k][j]
    float g1 = c1[b * D1 + j];
    #pragma unroll 8
    for (int k = 0; k < D1; ++k) g1 += h2L[k] * W1[(size_t)k * D1 + j];

    // g2 = b1 + h1 @ W1^T + h3 @ W2
    //   (h1@W1^T)[j] = sum_k h1[k] * W1[j][k];  (h3@W2)[j] = sum_{k<10} h3[k]*W2[k][j]
    float g2 = b1[j];
    const float* w1r = W1 + (size_t)j * D1;
    #pragma unroll 8
    for (int k = 0; k < D1; ++k) g2 += h1L[k] * w1r[k];
    #pragma unroll
    for (int k = 0; k < D3; ++k) g2 += h3L[k] * W2[(size_t)k * D1 + j];

    dst[b * D1 + j]          = tanhf(g1);
    dst[H2_REL + b * D1 + j] = tanhf(g2);

    // g3 = b2 + h2 @ W2^T        -> [j] = sum_k h2[k] * W2[j][k]   (j < 10)
    if (j < D3) {
        float g3 = b2[j];
        const float* w2r = W2 + (size_t)j * D1;
        #pragma unroll 8
        for (int k = 0; k < D1; ++k) g3 += h2L[k] * w2r[k];
        dst[H3_REL + b * D3 + j] = tanhf(g3);
    }
}

// ---- epilogue: out <- (h1, h2, h3) flat fp32
__global__ __launch_bounds__(128)
void k_out(const float* __restrict__ A, float* __restrict__ out)
{
    const size_t b = blockIdx.x;
    const int j = threadIdx.x;
    out[b * D1 + j]          = A[b * D1 + j];
    out[H2_REL + b * D1 + j] = A[H2_REL + b * D1 + j];
    if (j < D3) out[H3_REL + b * D3 + j] = A[H3_REL + b * D3 + j];
}

extern "C" void kernel_launch(void* const* d_in, const int* in_sizes, int n_in,
                              void* d_out, int out_size, void* d_ws, size_t ws_size,
                              hipStream_t stream) {
    // inputs: 0:x 1:y(unused) 2:n1 3:n2 4:n3 5:W0 6:b0 7:W1 8:b1 9:W2 10:b2 11:T(=60 hard-coded)
    const float* x  = (const float*)d_in[0];
    const float* n1 = (const float*)d_in[2];
    const float* n2 = (const float*)d_in[3];
    const float* n3 = (const float*)d_in[4];
    const float* W0 = (const float*)d_in[5];
    const float* b0 = (const float*)d_in[6];
    const float* W1 = (const float*)d_in[7];
    const float* b1 = (const float*)d_in[8];
    const float* W2 = (const float*)d_in[9];
    const float* b2 = (const float*)d_in[10];
    float* ws  = (float*)d_ws;
    float* c1  = ws + C1_OFF;
    float* A   = ws + A_OFF;
    float* B   = ws + B_OFF;
    float* out = (float*)d_out;

    k_init<<<NB, 128, 0, stream>>>(n1, n2, n3, A);
    k_c1<<<NB, 128, 0, stream>>>(x, W0, b0, c1);
    float* s = A; float* d = B;
    for (int t = 0; t < TSTEPS; ++t) {
        k_step<<<NB, 128, 0, stream>>>(s, d, c1, W1, b1, W2, b2);
        float* tmp = s; s = d; d = tmp;
    }
    // after 60 steps, final state is in s
    k_out<<<NB, 128, 0, stream>>>(s, out);
}

// Round 10
// 1786.408 us; speedup vs baseline: 6.2342x; 6.2342x over previous
//
#include <hip/hip_runtime.h>

// EqProp MLP relaxation (784->128->128->10, B=16384, T=60), FUSED all-FP32 kernel.
// PRECISION FINDING (R5-R9): W1 ~ N(0,1/128) puts the tanh relaxation at the
// edge of chaos (spectral radius ~1). (I-J)^-1 amplifies c1 bias ~260x (R9:
// f16 c1 -> 0.47 error) and per-step state quantization accumulates without
// decay (R5/R6/R8: f16 state -> ~1.0 error). Everything must be fp32-grade.
// Structure: rows are independent -> full fusion is exact with per-block
// Jacobi barriers. State fp32 in LDS; c1 = x@W0^T+b0 (loop-invariant) lives in
// REGISTERS (each thread's 4x4 tile is only ever read by that thread).
// Thread tile: 4 rows x 4 cols. jg=tid&31 (cols 4jg..4jg+3), rg=tid>>5 (rows
// 4rg..4rg+3). 32 rows/block, 512 blocks, 256 threads.
//   h1' = tanh(c1 + h2@W1)
//   h2' = tanh(b1 + h1@W1^T + h3@W2)
//   h3' = tanh(b2 + h2@W2^T)
// W1^T pre-transposed to d_ws so step reads are float4-coalesced.

#define NB 16384
#define D0 784
#define D1 128
#define D3 10
#define TSTEPS 60
#define NT 256
#define ROWS 32
#define NBLK 512
#define H2O ((size_t)NB * D1)
#define H3O ((size_t)2 * NB * D1)

__global__ __launch_bounds__(256)
void k_prep_t(const float* __restrict__ W1, float* __restrict__ w1t)
{
    int gid = blockIdx.x * 256 + threadIdx.x;    // 16384 = 64 blocks
    int k = gid >> 7, j = gid & 127;
    w1t[gid] = W1[j * D1 + k];                   // w1t[k][j] = W1[j][k]
}

__global__ __launch_bounds__(NT)
void k_fused(const float* __restrict__ x,
             const float* __restrict__ n1, const float* __restrict__ n2,
             const float* __restrict__ n3,
             const float* __restrict__ W0, const float* __restrict__ b0,
             const float* __restrict__ W1, const float* __restrict__ w1t,
             const float* __restrict__ b1,
             const float* __restrict__ W2, const float* __restrict__ b2,
             float* __restrict__ out)
{
    __shared__ float h1L[ROWS * D1];     // 16 KB
    __shared__ float h2L[ROWS * D1];     // 16 KB
    __shared__ float h3L[ROWS * 12];     // 1.5 KB (cols 10,11 pad, never read)
    float* xs = h1L;                     // 32x64 x-chunk staging aliases h1L (phase 1 only)

    const int tid = threadIdx.x;
    const int jg = tid & 31, rg = tid >> 5;
    const int j0 = jg * 4, r0 = rg * 4;
    const size_t row0 = (size_t)blockIdx.x * ROWS;

    // ---------------- phase 1: c1 = x @ W0^T + b0, kept in registers
    float c1r[4][4];
    #pragma unroll
    for (int i = 0; i < 4; ++i)
        #pragma unroll
        for (int l = 0; l < 4; ++l) c1r[i][l] = 0.f;

    for (int ch = 0; ch < 13; ++ch) {            // 784 = 12*64 + 16
        const int kb = ch * 64;
        const int klen = (ch < 12) ? 64 : 16;
        const int nv4 = klen >> 2;
        for (int q = tid; q < ROWS * nv4; q += NT) {
            int r = q / nv4, c4 = q - r * nv4;
            *(float4*)&xs[r * 64 + 4 * c4] =
                *(const float4*)(x + (row0 + r) * D0 + kb + 4 * c4);
        }
        __syncthreads();
        for (int k = 0; k < klen; ++k) {
            float xr[4];
            #pragma unroll
            for (int i = 0; i < 4; ++i) xr[i] = xs[(r0 + i) * 64 + k];  // LDS broadcast
            #pragma unroll
            for (int l = 0; l < 4; ++l) {
                float w = W0[(size_t)(j0 + l) * D0 + kb + k];           // L1-resident stream
                #pragma unroll
                for (int i = 0; i < 4; ++i) c1r[i][l] += xr[i] * w;
            }
        }
        __syncthreads();
    }
    float b1r[4];
    #pragma unroll
    for (int l = 0; l < 4; ++l) {
        float bb = b0[j0 + l];
        #pragma unroll
        for (int i = 0; i < 4; ++i) c1r[i][l] += bb;
        b1r[l] = b1[j0 + l];
    }
    const float b2r = (jg < D3) ? b2[jg] : 0.f;

    // ---------------- init state (xs alias done; barrier above protects)
    for (int q = tid; q < ROWS * 32; q += NT) {
        int r = q >> 5, c4 = q & 31;
        *(float4*)&h1L[r * D1 + 4 * c4] = *(const float4*)(n1 + (row0 + r) * D1 + 4 * c4);
        *(float4*)&h2L[r * D1 + 4 * c4] = *(const float4*)(n2 + (row0 + r) * D1 + 4 * c4);
    }
    for (int q = tid; q < ROWS * D3; q += NT) {
        int r = q / D3, c = q - r * D3;
        h3L[r * 12 + c] = n3[(row0 + r) * D3 + c];
    }
    __syncthreads();

    // ---------------- T synchronous Jacobi steps
    for (int t = 0; t < TSTEPS; ++t) {
        float a1[4][4], a2[4][4], a3[4];
        #pragma unroll
        for (int i = 0; i < 4; ++i) {
            #pragma unroll
            for (int l = 0; l < 4; ++l) { a1[i][l] = c1r[i][l]; a2[i][l] = b1r[l]; }
            a3[i] = b2r;
        }
        for (int k = 0; k < D1; ++k) {
            float h2r[4], h1r[4];
            #pragma unroll
            for (int i = 0; i < 4; ++i) {
                h2r[i] = h2L[(r0 + i) * D1 + k];   // 2 addrs/wave -> broadcast, free
                h1r[i] = h1L[(r0 + i) * D1 + k];
            }
            float4 wa = *(const float4*)(W1  + (size_t)k * D1 + j0);  // coalesced 512B/wave
            float4 wb = *(const float4*)(w1t + (size_t)k * D1 + j0);
            #pragma unroll
            for (int i = 0; i < 4; ++i) {
                a1[i][0] += h2r[i] * wa.x;  a1[i][1] += h2r[i] * wa.y;
                a1[i][2] += h2r[i] * wa.z;  a1[i][3] += h2r[i] * wa.w;
                a2[i][0] += h1r[i] * wb.x;  a2[i][1] += h1r[i] * wb.y;
                a2[i][2] += h1r[i] * wb.z;  a2[i][3] += h1r[i] * wb.w;
            }
        }
        #pragma unroll
        for (int kk = 0; kk < D3; ++kk) {          // g2 += h3 @ W2
            float4 wc = *(const float4*)(W2 + (size_t)kk * D1 + j0);
            #pragma unroll
            for (int i = 0; i < 4; ++i) {
                float h3v = h3L[(r0 + i) * 12 + kk];
                a2[i][0] += h3v * wc.x; a2[i][1] += h3v * wc.y;
                a2[i][2] += h3v * wc.z; a2[i][3] += h3v * wc.w;
            }
        }
        if (jg < D3) {                             // g3 = b2 + h2 @ W2^T (col jg)
            for (int k = 0; k < D1; ++k) {
                float w = W2[(size_t)jg * D1 + k];
                #pragma unroll
                for (int i = 0; i < 4; ++i) a3[i] += h2L[(r0 + i) * D1 + k] * w;
            }
        }
        __syncthreads();   // all reads of old state complete
        #pragma unroll
        for (int i = 0; i < 4; ++i)
            #pragma unroll
            for (int l = 0; l < 4; ++l) {
                h1L[(r0 + i) * D1 + j0 + l] = tanhf(a1[i][l]);
                h2L[(r0 + i) * D1 + j0 + l] = tanhf(a2[i][l]);
            }
        if (jg < D3) {
            #pragma unroll
            for (int i = 0; i < 4; ++i) h3L[(r0 + i) * 12 + jg] = tanhf(a3[i]);
        }
        __syncthreads();   // new state visible
    }

    // ---------------- epilogue: (h1, h2, h3) fp32, coalesced
    for (int q = tid; q < ROWS * 32; q += NT) {
        int r = q >> 5, c4 = q & 31;
        *(float4*)(out + (row0 + r) * D1 + 4 * c4)       = *(const float4*)&h1L[r * D1 + 4 * c4];
        *(float4*)(out + H2O + (row0 + r) * D1 + 4 * c4) = *(const float4*)&h2L[r * D1 + 4 * c4];
    }
    for (int q = tid; q < ROWS * D3; q += NT) {
        int r = q / D3, c = q - r * D3;
        out[H3O + (row0 + r) * D3 + c] = h3L[r * 12 + c];
    }
}

extern "C" void kernel_launch(void* const* d_in, const int* in_sizes, int n_in,
                              void* d_out, int out_size, void* d_ws, size_t ws_size,
                              hipStream_t stream) {
    // inputs: 0:x 1:y 2:n1 3:n2 4:n3 5:W0 6:b0 7:W1 8:b1 9:W2 10:b2 11:T(=60 hard-coded)
    const float* x  = (const float*)d_in[0];
    const float* n1 = (const float*)d_in[2];
    const float* n2 = (const float*)d_in[3];
    const float* n3 = (const float*)d_in[4];
    const float* W0 = (const float*)d_in[5];
    const float* b0 = (const float*)d_in[6];
    const float* W1 = (const float*)d_in[7];
    const float* b1 = (const float*)d_in[8];
    const float* W2 = (const float*)d_in[9];
    const float* b2 = (const float*)d_in[10];
    float* w1t = (float*)d_ws;                   // 64 KB scratch for W1^T

    k_prep_t<<<64, 256, 0, stream>>>(W1, w1t);
    k_fused<<<NBLK, NT, 0, stream>>>(x, n1, n2, n3, W0, b0, W1, w1t, b1, W2, b2,
                                     (float*)d_out);

    hipError_t e = hipGetLastError();
    if (e != hipSuccess) {   // surface launch error as fp32 1000+e (free on success)
        static float code[4];
        code[0] = code[1] = code[2] = code[3] = 1000.0f + (float)(int)e;
        hipMemcpyAsync(d_out, code, 4 * sizeof(float), hipMemcpyHostToDevice, stream);
    }
}